// Round 10
// baseline (182.087 us; speedup 1.0000x reference)
//
#include <hip/hip_runtime.h>

#define S_LEN 2048
#define DMODEL 1024
#define NBATCH 4

typedef unsigned short u16;
typedef __bf16 bf16x8 __attribute__((ext_vector_type(8)));
typedef float f32x4 __attribute__((ext_vector_type(4)));

typedef __attribute__((address_space(3))) unsigned lds_u32;
typedef const __attribute__((address_space(1))) unsigned glb_u32;

__device__ __forceinline__ u16 f2bf(float f) {
  union { float f; unsigned u; } v;
  v.f = f;
  unsigned r = v.u + 0x7fffu + ((v.u >> 16) & 1u);
  return (u16)(r >> 16);
}

__device__ __forceinline__ float bf2f(u16 h) {
  union { unsigned u; float f; } v;
  v.u = ((unsigned)h) << 16;
  return v.f;
}

// ---------------- convert x: fp32 -> bf16, flat ----------------
__global__ void convert_x_kernel(const float* __restrict__ x, u16* __restrict__ xb, long n) {
  long i = ((long)blockIdx.x * blockDim.x + threadIdx.x) * 4;
  long stride = (long)gridDim.x * blockDim.x * 4;
  for (; i < n; i += stride) {
    float4 v = *reinterpret_cast<const float4*>(x + i);
    ushort4 o;
    o.x = f2bf(v.x); o.y = f2bf(v.y); o.z = f2bf(v.z); o.w = f2bf(v.w);
    *reinterpret_cast<ushort4*>(xb + i) = o;
  }
}

// ---------------- transpose-convert W: Wt[n][k] = bf16(W[k][n]), 1024x1024 ----------------
__global__ void transpose_w_kernel(const float* __restrict__ W, u16* __restrict__ Wt) {
  __shared__ float tile[32][33];
  int tx = threadIdx.x, ty = threadIdx.y;
  int k0 = blockIdx.x * 32, n0 = blockIdx.y * 32;
#pragma unroll
  for (int i = 0; i < 32; i += 8)
    tile[ty + i][tx] = W[(long)(k0 + ty + i) * DMODEL + n0 + tx];
  __syncthreads();
#pragma unroll
  for (int i = 0; i < 32; i += 8)
    Wt[(long)(n0 + ty + i) * DMODEL + k0 + tx] = f2bf(tile[tx][ty + i]);
}

// ================= 128x256 NT GEMM, BK=32, 3-buffer depth-2 pipeline =================
// C[M][N] = A[M][K]*B[N][K]^T. BM=128, BN=256, BK=32, 512 thr = 8 waves (2M x 4N),
// wave tile 64x64 (4m x 4n frags of 16x16x32).
// LDS: 3 bufs x (A 8KB | B 16KB) = 72 KiB; 1024B subtiles [16r][32c] bf16 with
// st_16x32 swizzle; staged LINEAR via global_load_lds from inverse-swizzled per-lane
// global source; frag reads apply the same involution (frag_off).
// Depth-2 counted pipeline (T4): step g issues stage g+2 -> buf (g+2)%3 (3 gloads),
// reads 8 frags of buf g%3, lgkmcnt(0), 16 MFMA, then vmcnt(3) — forces stage g+1
// complete while stage g+2's 3 loads stay in flight (latency budget = 2 steps).
// Tail (g >= NT-2): no issue, vmcnt(0).
// WAR: step g+1's STG overwrites buf g%3; all readers drained at step g's lgkmcnt(0)
// before step g's closing barrier. RAW: the end-of-step wait + barrier.
// MODE: 0 = plain; 1 = scores (skip bn*2 > bm); 3 = split-K PV (bz = batch*4 + chunk)
// CMODE: 1 = bf16 row-major (+bz*sCz); 3 = fused QKV epilogue;
//        4 = PV epilogue (bm<4 -> f32 direct to Cptr2; else bf16 partial slot)
template<int CMODE, int MODE>
__global__ __launch_bounds__(512) void gemm_bk32(
    const u16* __restrict__ A, const u16* __restrict__ B,
    void* __restrict__ Cptr, void* __restrict__ Cptr2,
    int lda, int ldb, int ldc, int Kdim,
    long sAz, long sBz, long sCz)
{
  int bm = blockIdx.x, bn = blockIdx.y, bz = blockIdx.z;
  int k0 = 0, Keff = Kdim, slot = 0;
  if constexpr (MODE == 1) {
    if (bn * 2 > bm) return;   // block entirely above diagonal
  }
  if constexpr (MODE == 3) {
    int c = bz & 3;
    bz >>= 2;                                  // batch
    int Klim = (bm + 1) * 128;
    k0 = c * 512;
    if (k0 >= Klim) return;
    int k1 = k0 + 512; if (k1 > Klim) k1 = Klim;
    Keff = k1 - k0;
    int q = bm >> 2, s = bm & 3;
    slot = bz * 40 + (q + 1) * (2 * q + s) + c;
  }
  int NT = Keff >> 5;   // K-steps of 32; >= 4 in all launches

  const u16* Ab = A + (long)bz * sAz + (long)bm * 128 * lda + k0;
  const u16* Bb = B + (long)bz * sBz + (long)bn * 256 * ldb + k0;

  __shared__ char lds[73728];   // 3 x 24 KiB

  int tid = threadIdx.x;
  int lane = tid & 63, w = tid >> 6;
  int wm = w >> 2, wn = w & 3;
  int l15 = lane & 15, lhi = lane >> 4;
  int frag_off = (l15 * 64 + lhi * 16) ^ (((lane >> 3) & 1) << 5);

  // staging source pre-swizzle (linear LDS dest, inverse-swizzled global src)
  int le = lane ^ ((lane >> 5) << 1);
  int lr = le >> 2;
  int kb = (le & 3) * 8;

  const u16* Asrc = Ab + (long)(w * 16 + lr) * lda + kb;
  const u16* Bsrc = Bb + (long)(w * 16 + lr) * ldb + kb;

  // stage step T (k = T*32) into buffer index BI (0..2)
#define STG32(T, BI) do { \
    const u16* _sa = Asrc + (T) * 32; \
    const u16* _sb = Bsrc + (T) * 32; \
    char* _base = lds + (BI) * 24576; \
    __builtin_amdgcn_global_load_lds((glb_u32*)_sa, (lds_u32*)(_base + w * 1024), 16, 0, 0); \
    __builtin_amdgcn_global_load_lds((glb_u32*)_sb, (lds_u32*)(_base + 8192 + w * 1024), 16, 0, 0); \
    __builtin_amdgcn_global_load_lds((glb_u32*)(_sb + (long)128 * ldb), (lds_u32*)(_base + 8192 + (8 + w) * 1024), 16, 0, 0); \
  } while (0)

  f32x4 acc[4][4];
#pragma unroll
  for (int i = 0; i < 4; ++i)
#pragma unroll
    for (int j = 0; j < 4; ++j)
      acc[i][j] = (f32x4){0.f, 0.f, 0.f, 0.f};

  // prologue: stages 0 and 1 in flight; force stage 0 resident (vmcnt(3) keeps 1 pending)
  STG32(0, 0);
  STG32(1, 1);
  asm volatile("s_waitcnt vmcnt(3)" ::: "memory");
  __builtin_amdgcn_s_barrier();

  int buf = 0;
  for (int g = 0; g < NT; ++g) {
    bool issue = (g + 2 < NT);
    if (issue) {
      int b2 = buf + 2; if (b2 >= 3) b2 -= 3;
      STG32(g + 2, b2);
    }

    const char* _Al = lds + buf * 24576;
    const char* _Bl = _Al + 8192;
    bf16x8 af[4], bf[4];
#pragma unroll
    for (int i = 0; i < 4; ++i)
      af[i] = *(const bf16x8*)(_Al + (wm * 4 + i) * 1024 + frag_off);
#pragma unroll
    for (int j = 0; j < 4; ++j)
      bf[j] = *(const bf16x8*)(_Bl + (wn * 4 + j) * 1024 + frag_off);

    asm volatile("s_waitcnt lgkmcnt(0)" ::: "memory");
    __builtin_amdgcn_sched_barrier(0);
    __builtin_amdgcn_s_setprio(1);
#pragma unroll
    for (int i = 0; i < 4; ++i)
#pragma unroll
      for (int j = 0; j < 4; ++j)
        acc[i][j] = __builtin_amdgcn_mfma_f32_16x16x32_bf16(af[i], bf[j], acc[i][j], 0, 0, 0);
    __builtin_amdgcn_s_setprio(0);

    if (issue) {
      asm volatile("s_waitcnt vmcnt(3)" ::: "memory");   // stage g+1 resident; g+2 in flight
    } else {
      asm volatile("s_waitcnt vmcnt(0)" ::: "memory");   // tail: drain remaining
    }
    __builtin_amdgcn_s_barrier();

    ++buf; if (buf >= 3) buf = 0;
  }
#undef STG32

  // epilogue: C/D frag mapping: row = base + lhi*4 + reg, col = base + l15
#pragma unroll
  for (int i = 0; i < 4; ++i)
#pragma unroll
    for (int j = 0; j < 4; ++j) {
      int rl = wm * 64 + i * 16 + lhi * 4;            // row within 128-band
      int col = bn * 256 + wn * 64 + j * 16 + l15;    // global col
      f32x4 v = acc[i][j];
      if constexpr (CMODE == 1) {
        u16* C = (u16*)Cptr + (long)bz * sCz;
        int r0 = bm * 128 + rl;
#pragma unroll
        for (int r = 0; r < 4; ++r)
          C[(long)(r0 + r) * ldc + col] = f2bf(v[r]);
      } else if constexpr (CMODE == 4) {
        if (bm < 4) {
          float* O = (float*)Cptr2;
          long r0 = (long)bz * S_LEN + bm * 128 + rl;
#pragma unroll
          for (int r = 0; r < 4; ++r)
            O[(r0 + r) * 1024 + col] = v[r];
        } else {
          u16* Pp = (u16*)Cptr + (long)slot * 131072;
#pragma unroll
          for (int r = 0; r < 4; ++r)
            Pp[(long)(rl + r) * 1024 + col] = f2bf(v[r]);
        }
      } else {
        // fused QKV: cols [0,1024)=Q, [1024,2048)=K row-major bf16; [2048,3072)=V -> Vt[b][e][s]
        int r0 = bm * 128 + rl;
        if (col < 2048) {
          u16* dst = (u16*)Cptr + (col >= 1024 ? 8388608 : 0);
          int c = col & 1023;
#pragma unroll
          for (int r = 0; r < 4; ++r)
            dst[(long)(r0 + r) * 1024 + c] = f2bf(v[r]);
        } else {
          u16* Vt = (u16*)Cptr + 16777216;
          int e = col - 2048;
          int bb = r0 >> 11, s = r0 & 2047;
          ushort4 u;
          u.x = f2bf(v[0]); u.y = f2bf(v[1]); u.z = f2bf(v[2]); u.w = f2bf(v[3]);
          *reinterpret_cast<ushort4*>(Vt + ((long)bb * 1024 + e) * 2048 + s) = u;
        }
      }
    }
}

// ---------------- one-pass causal row softmax: sc(bf16, unscaled) -> P(bf16) ----------------
__global__ __launch_bounds__(256) void softmax1p(const u16* __restrict__ sc,
                                                 u16* __restrict__ P) {
  int q = blockIdx.x, b = blockIdx.y;
  const u16* srow = sc + ((long)b * S_LEN + q) * S_LEN;
  u16* prow = P + ((long)b * S_LEN + q) * S_LEN;
  int n = q + 1;
  int nz = ((q >> 8) + 1) << 8;
  int tid = threadIdx.x;
  int j0 = tid * 8;
  const float scale = 0.03125f;

  __shared__ float red[8];

  float vs[8];
#pragma unroll
  for (int e = 0; e < 8; ++e) vs[e] = -1e30f;
  if (j0 < n) {
    ushort4 a = *reinterpret_cast<const ushort4*>(srow + j0);
    ushort4 c = *reinterpret_cast<const ushort4*>(srow + j0 + 4);
    vs[0] = bf2f(a.x) * scale; vs[1] = bf2f(a.y) * scale;
    vs[2] = bf2f(a.z) * scale; vs[3] = bf2f(a.w) * scale;
    vs[4] = bf2f(c.x) * scale; vs[5] = bf2f(c.y) * scale;
    vs[6] = bf2f(c.z) * scale; vs[7] = bf2f(c.w) * scale;
#pragma unroll
    for (int e = 0; e < 8; ++e)
      if (j0 + e >= n) vs[e] = -1e30f;
  }

  float m = -1e30f;
#pragma unroll
  for (int e = 0; e < 8; ++e) m = fmaxf(m, vs[e]);
#pragma unroll
  for (int off = 32; off > 0; off >>= 1) m = fmaxf(m, __shfl_xor(m, off, 64));
  if ((tid & 63) == 0) red[tid >> 6] = m;
  __syncthreads();
  float ms = fmaxf(fmaxf(red[0], red[1]), fmaxf(red[2], red[3]));

  float p[8];
  float s = 0.f;
#pragma unroll
  for (int e = 0; e < 8; ++e) { p[e] = __expf(vs[e] - ms); s += (j0 + e < n) ? p[e] : 0.f; }
#pragma unroll
  for (int off = 32; off > 0; off >>= 1) s += __shfl_xor(s, off, 64);
  __syncthreads();
  if ((tid & 63) == 0) red[4 + (tid >> 6)] = s;
  __syncthreads();
  float inv = 1.f / (red[4] + red[5] + red[6] + red[7]);

  if (j0 < nz) {
    ushort4 o0, o1;
    o0.x = (j0 + 0 < n) ? f2bf(p[0] * inv) : (u16)0;
    o0.y = (j0 + 1 < n) ? f2bf(p[1] * inv) : (u16)0;
    o0.z = (j0 + 2 < n) ? f2bf(p[2] * inv) : (u16)0;
    o0.w = (j0 + 3 < n) ? f2bf(p[3] * inv) : (u16)0;
    o1.x = (j0 + 4 < n) ? f2bf(p[4] * inv) : (u16)0;
    o1.y = (j0 + 5 < n) ? f2bf(p[5] * inv) : (u16)0;
    o1.z = (j0 + 6 < n) ? f2bf(p[6] * inv) : (u16)0;
    o1.w = (j0 + 7 < n) ? f2bf(p[7] * inv) : (u16)0;
    *reinterpret_cast<ushort4*>(prow + j0) = o0;
    *reinterpret_cast<ushort4*>(prow + j0 + 4) = o1;
  }
}

// ---------------- reduce split-K partials -> out (f32), rows >= 512 only ----------------
__global__ __launch_bounds__(256) void reduce_pv(const u16* __restrict__ partial,
                                                 float* __restrict__ out) {
  long i4 = (long)blockIdx.x * 256 + threadIdx.x;
  int e4 = (int)(i4 & 255);
  long t = i4 >> 8;
  int b = (int)(t / 1536);
  int rr = 512 + (int)(t % 1536);
  int bm = rr >> 7, r128 = rr & 127;
  int q = bm >> 2, s = bm & 3;
  int off = (q + 1) * (2 * q + s);
  int cnt = q + 1;

  const u16* base = partial + ((long)(b * 40 + off)) * 131072 + (long)r128 * 1024 + e4 * 4;
  float a0 = 0.f, a1 = 0.f, a2 = 0.f, a3 = 0.f;
  for (int c = 0; c < cnt; ++c) {
    ushort4 vv = *reinterpret_cast<const ushort4*>(base + (long)c * 131072);
    a0 += bf2f(vv.x); a1 += bf2f(vv.y); a2 += bf2f(vv.z); a3 += bf2f(vv.w);
  }
  float4 o = make_float4(a0, a1, a2, a3);
  *reinterpret_cast<float4*>(out + ((long)b * 2048 + rr) * 1024 + e4 * 4) = o;
}

// ---------------- launch ----------------
extern "C" void kernel_launch(void* const* d_in, const int* in_sizes, int n_in,
                              void* d_out, int out_size, void* d_ws, size_t ws_size,
                              hipStream_t stream) {
  const float* x  = (const float*)d_in[0];
  const float* Wq = (const float*)d_in[1];
  const float* Wk = (const float*)d_in[2];
  const float* Wv = (const float*)d_in[3];
  float* out = (float*)d_out;

  char* ws = (char*)d_ws;
  u16* xb   = (u16*)(ws);
  u16* wtb  = (u16*)(ws + 16777216);
  u16* Qb   = (u16*)(ws + 23068672);
  u16* Kb   = (u16*)(ws + 39845888);
  u16* Vtb  = (u16*)(ws + 56623104);
  u16* scb  = (u16*)(ws + 73400320);
  u16* part = (u16*)(ws + 73400320);
  u16* P    = (u16*)(ws + 115343360);

  long nx = (long)NBATCH * S_LEN * DMODEL;
  convert_x_kernel<<<2048, 256, 0, stream>>>(x, xb, nx);

  dim3 tb(32, 8);
  transpose_w_kernel<<<dim3(32, 32), tb, 0, stream>>>(Wq, wtb);
  transpose_w_kernel<<<dim3(32, 32), tb, 0, stream>>>(Wk, wtb + 1024 * 1024);
  transpose_w_kernel<<<dim3(32, 32), tb, 0, stream>>>(Wv, wtb + 2 * 1024 * 1024);

  // fused QKV projection: M=8192, N=3072 (Q|K|V), K=1024
  gemm_bk32<3, 0><<<dim3(64, 12, 1), 512, 0, stream>>>(
      xb, wtb, Qb, nullptr, DMODEL, DMODEL, 0, DMODEL, 0, 0, 0);

  // scores (unscaled, bf16): per batch S = Q*K^T, causal skip at 128-row bands
  gemm_bk32<1, 1><<<dim3(16, 8, 4), 512, 0, stream>>>(
      Qb, Kb, scb, nullptr, DMODEL, DMODEL, S_LEN, DMODEL,
      (long)S_LEN * DMODEL, (long)S_LEN * DMODEL, (long)S_LEN * S_LEN);

  softmax1p<<<dim3(S_LEN, NBATCH), 256, 0, stream>>>(scb, P);

  // O = P * V, split-K chunks of 512: bm<4 direct f32, bm>=4 bf16 partials
  gemm_bk32<4, 3><<<dim3(16, 4, 16), 512, 0, stream>>>(
      P, Vtb, part, out, S_LEN, S_LEN, 0, S_LEN,
      (long)S_LEN * S_LEN, (long)DMODEL * S_LEN, 0);

  // reduce partials into f32 out (rows >= 512)
  reduce_pv<<<6144, 256, 0, stream>>>(part, out);
}

// Round 11
// 173.671 us; speedup vs baseline: 1.0485x; 1.0485x over previous
//
#include <hip/hip_runtime.h>

#define S_LEN 2048
#define DMODEL 1024
#define NBATCH 4

typedef unsigned short u16;
typedef __bf16 bf16x8 __attribute__((ext_vector_type(8)));
typedef float f32x4 __attribute__((ext_vector_type(4)));

typedef __attribute__((address_space(3))) unsigned lds_u32;
typedef const __attribute__((address_space(1))) unsigned glb_u32;

__device__ __forceinline__ u16 f2bf(float f) {
  union { float f; unsigned u; } v;
  v.f = f;
  unsigned r = v.u + 0x7fffu + ((v.u >> 16) & 1u);
  return (u16)(r >> 16);
}

__device__ __forceinline__ float bf2f(u16 h) {
  union { unsigned u; float f; } v;
  v.u = ((unsigned)h) << 16;
  return v.f;
}

// XCD-aware block remap (T1). Requires nwg % 8 == 0 (all our grids: 768, 256, 512).
// HW assigns hw-id round-robin to XCDs; this makes work-ids contiguous per XCD.
#define XCD_SWZ() do { \
    int _nwg = gridDim.x * gridDim.y * gridDim.z; \
    int _hw = blockIdx.x + gridDim.x * (blockIdx.y + gridDim.y * blockIdx.z); \
    int _q = _nwg >> 3; \
    int _w = (_hw & 7) * _q + (_hw >> 3); \
    bm = _w % gridDim.x; _w /= gridDim.x; \
    bn = _w % gridDim.y; bz = _w / gridDim.y; \
  } while (0)

// ---------------- convert x: fp32 -> bf16, flat ----------------
__global__ void convert_x_kernel(const float* __restrict__ x, u16* __restrict__ xb, long n) {
  long i = ((long)blockIdx.x * blockDim.x + threadIdx.x) * 4;
  long stride = (long)gridDim.x * blockDim.x * 4;
  for (; i < n; i += stride) {
    float4 v = *reinterpret_cast<const float4*>(x + i);
    ushort4 o;
    o.x = f2bf(v.x); o.y = f2bf(v.y); o.z = f2bf(v.z); o.w = f2bf(v.w);
    *reinterpret_cast<ushort4*>(xb + i) = o;
  }
}

// ---------------- transpose-convert all 3 W: Wt[z][n][k] = bf16(W[k][n]) ----------------
__global__ void transpose_w3_kernel(const float* __restrict__ Wq, const float* __restrict__ Wk,
                                    const float* __restrict__ Wv, u16* __restrict__ Wt) {
  const float* W = blockIdx.z == 0 ? Wq : (blockIdx.z == 1 ? Wk : Wv);
  u16* dst = Wt + (long)blockIdx.z * 1024 * 1024;
  __shared__ float tile[32][33];
  int tx = threadIdx.x, ty = threadIdx.y;
  int k0 = blockIdx.x * 32, n0 = blockIdx.y * 32;
#pragma unroll
  for (int i = 0; i < 32; i += 8)
    tile[ty + i][tx] = W[(long)(k0 + ty + i) * DMODEL + n0 + tx];
  __syncthreads();
#pragma unroll
  for (int i = 0; i < 32; i += 8)
    dst[(long)(n0 + ty + i) * DMODEL + k0 + tx] = f2bf(tile[tx][ty + i]);
}

// ================= 256x256 NT GEMM, 4-phase/K-tile (r5 engine; scores) =================
#define STG(SRCP, LD, ISB, H, T, BUFB) do { \
    const u16* _s = (SRCP) + (long)(H) * 128 * (LD) + (T) * 64; \
    char* _d = lds + (BUFB) * 65536 + ((ISB) ? 32768 : 0) + ((H) * 8 + w) * 2048; \
    __builtin_amdgcn_global_load_lds((glb_u32*)_s, (lds_u32*)_d, 16, 0, 0); \
    __builtin_amdgcn_global_load_lds((glb_u32*)(_s + 32), (lds_u32*)(_d + 1024), 16, 0, 0); \
  } while (0)

#define READ_A(QM) do { \
    _Pragma("unroll") \
    for (int _i = 0; _i < 4; ++_i) { \
      int _mp = (QM) * 8 + wm * 4 + _i; \
      af[_i][0] = *(const bf16x8*)(_Al + (_mp * 2 + 0) * 1024 + frag_off); \
      af[_i][1] = *(const bf16x8*)(_Al + (_mp * 2 + 1) * 1024 + frag_off); \
    } \
  } while (0)

#define READ_BQ(DST, QN) do { \
    _Pragma("unroll") \
    for (int _j = 0; _j < 2; ++_j) { \
      int _np = (QN) * 8 + wn * 2 + _j; \
      DST[_j][0] = *(const bf16x8*)(_Bl + (_np * 2 + 0) * 1024 + frag_off); \
      DST[_j][1] = *(const bf16x8*)(_Bl + (_np * 2 + 1) * 1024 + frag_off); \
    } \
  } while (0)

#define MFMA16(QM, QN, BREG) do { \
    _Pragma("unroll") \
    for (int _i = 0; _i < 4; ++_i) \
      _Pragma("unroll") \
      for (int _j = 0; _j < 2; ++_j) { \
        acc[QM][QN][_i][_j] = __builtin_amdgcn_mfma_f32_16x16x32_bf16(af[_i][0], BREG[_j][0], acc[QM][QN][_i][_j], 0, 0, 0); \
        acc[QM][QN][_i][_j] = __builtin_amdgcn_mfma_f32_16x16x32_bf16(af[_i][1], BREG[_j][1], acc[QM][QN][_i][_j], 0, 0, 0); \
      } \
  } while (0)

__global__ __launch_bounds__(512, 2) void gemm256_sc(
    const u16* __restrict__ A, const u16* __restrict__ B, u16* __restrict__ Cptr,
    int lda, int ldb, int ldc, int Kdim,
    long sAz, long sBz, long sCz)
{
  int bm, bn, bz;
  XCD_SWZ();
  if (bn > bm) return;           // causal block skip
  int NT = Kdim >> 6;

  const u16* Ab = A + (long)bz * sAz + (long)bm * 256 * lda;
  const u16* Bb = B + (long)bz * sBz + (long)bn * 256 * ldb;

  __shared__ char lds[131072];

  int tid = threadIdx.x;
  int lane = tid & 63, w = tid >> 6;
  int wm = w >> 2, wn = w & 3;
  int l15 = lane & 15, lhi = lane >> 4;
  int frag_off = (l15 * 64 + lhi * 16) ^ (((lane >> 3) & 1) << 5);

  int le = lane ^ ((lane >> 5) << 1);
  int lr = le >> 2;
  int kb = (le & 3) * 8;

  const u16* Asrc = Ab + (long)(w * 16 + lr) * lda + kb;
  const u16* Bsrc = Bb + (long)(w * 16 + lr) * ldb + kb;

  f32x4 acc[2][2][4][2];
#pragma unroll
  for (int a = 0; a < 2; ++a)
#pragma unroll
    for (int b = 0; b < 2; ++b)
#pragma unroll
      for (int c = 0; c < 4; ++c)
#pragma unroll
        for (int d = 0; d < 2; ++d)
          acc[a][b][c][d] = (f32x4){0.f, 0.f, 0.f, 0.f};

  STG(Asrc, lda, 0, 0, 0, 0); STG(Bsrc, ldb, 1, 0, 0, 0);
  STG(Asrc, lda, 0, 1, 0, 0); STG(Bsrc, ldb, 1, 1, 0, 0);
  STG(Asrc, lda, 0, 0, 1, 1); STG(Bsrc, ldb, 1, 0, 1, 1);
  asm volatile("s_waitcnt vmcnt(4)" ::: "memory");
  __builtin_amdgcn_s_barrier();

  for (int g = 0; g < NT; ++g) {
    int buf = g & 1;
    int t1 = g + 1; if (t1 >= NT) t1 -= NT;
    int t2 = g + 2; if (t2 >= NT) t2 -= NT;
    const char* _Al = lds + buf * 65536;
    const char* _Bl = _Al + 32768;
    bf16x8 af[4][2], b0[2][2], b1[2][2];

    READ_A(0);
    READ_BQ(b0, 0);
    STG(Asrc, lda, 0, 1, t1, buf ^ 1);
    __builtin_amdgcn_s_barrier();
    asm volatile("s_waitcnt lgkmcnt(0)" ::: "memory");
    __builtin_amdgcn_sched_barrier(0);
    __builtin_amdgcn_s_setprio(1);
    MFMA16(0, 0, b0);
    __builtin_amdgcn_s_setprio(0);
    __builtin_amdgcn_s_barrier();

    READ_BQ(b1, 1);
    STG(Bsrc, ldb, 1, 1, t1, buf ^ 1);
    __builtin_amdgcn_s_barrier();
    asm volatile("s_waitcnt lgkmcnt(0)" ::: "memory");
    __builtin_amdgcn_sched_barrier(0);
    __builtin_amdgcn_s_setprio(1);
    MFMA16(0, 1, b1);
    __builtin_amdgcn_s_setprio(0);
    __builtin_amdgcn_s_barrier();

    READ_A(1);
    STG(Asrc, lda, 0, 0, t2, buf);
    __builtin_amdgcn_s_barrier();
    asm volatile("s_waitcnt lgkmcnt(0)" ::: "memory");
    __builtin_amdgcn_sched_barrier(0);
    __builtin_amdgcn_s_setprio(1);
    MFMA16(1, 1, b1);
    __builtin_amdgcn_s_setprio(0);
    __builtin_amdgcn_s_barrier();

    STG(Bsrc, ldb, 1, 0, t2, buf);
    __builtin_amdgcn_s_barrier();
    __builtin_amdgcn_s_setprio(1);
    MFMA16(1, 0, b0);
    __builtin_amdgcn_s_setprio(0);
    asm volatile("s_waitcnt vmcnt(4)" ::: "memory");
    __builtin_amdgcn_s_barrier();
  }

  int Mbase = bm * 256, Nbase = bn * 256;
  u16* C = Cptr + (long)bz * sCz;
#pragma unroll
  for (int qm = 0; qm < 2; ++qm)
#pragma unroll
    for (int qn = 0; qn < 2; ++qn)
#pragma unroll
      for (int i = 0; i < 4; ++i)
#pragma unroll
        for (int j = 0; j < 2; ++j) {
          int r0 = Mbase + qm * 128 + wm * 64 + i * 16 + lhi * 4;
          int col = Nbase + qn * 128 + wn * 32 + j * 16 + l15;
          f32x4 v = acc[qm][qn][i][j];
#pragma unroll
          for (int r = 0; r < 4; ++r)
            C[(long)(r0 + r) * ldc + col] = f2bf(v[r]);
        }
}

// ================= 128x256 NT GEMM, BK=32, 3-buffer depth-2 pipeline =================
// (r10 engine). MODE: 0 = proj (CMODE=3 fused QKV epilogue);
//               4 = PV half-split: bz = batch*2 + h, h covers K in [h*1024, min((h+1)*1024, (bm+1)*128)).
// CMODE: 3 = fused QKV; 5 = PV f32 epilogue (h=0 -> out direct; h=1 -> f32 part2 rows 1024..2047)
template<int CMODE, int MODE>
__global__ __launch_bounds__(512) void gemm_bk32(
    const u16* __restrict__ A, const u16* __restrict__ B,
    void* __restrict__ Cptr, void* __restrict__ Cptr2,
    int lda, int ldb, int ldc, int Kdim,
    long sAz, long sBz, long sCz)
{
  int bm, bn, bz;
  XCD_SWZ();
  int k0 = 0, Keff = Kdim, h = 0;
  if constexpr (MODE == 4) {
    h = bz & 1;
    bz >>= 1;                                  // batch
    int Klim = (bm + 1) * 128;
    k0 = h * 1024;
    if (k0 >= Klim) return;
    int k1 = k0 + 1024; if (k1 > Klim) k1 = Klim;
    Keff = k1 - k0;
  }
  int NT = Keff >> 5;   // K-steps of 32; >= 4 in all launches

  const u16* Ab = A + (long)bz * sAz + (long)bm * 128 * lda + k0;
  const u16* Bb = B + (long)bz * sBz + (long)bn * 256 * ldb + k0;

  __shared__ char lds[73728];   // 3 x 24 KiB

  int tid = threadIdx.x;
  int lane = tid & 63, w = tid >> 6;
  int wm = w >> 2, wn = w & 3;
  int l15 = lane & 15, lhi = lane >> 4;
  int frag_off = (l15 * 64 + lhi * 16) ^ (((lane >> 3) & 1) << 5);

  int le = lane ^ ((lane >> 5) << 1);
  int lr = le >> 2;
  int kb = (le & 3) * 8;

  const u16* Asrc = Ab + (long)(w * 16 + lr) * lda + kb;
  const u16* Bsrc = Bb + (long)(w * 16 + lr) * ldb + kb;

#define STG32(T, BI) do { \
    const u16* _sa = Asrc + (T) * 32; \
    const u16* _sb = Bsrc + (T) * 32; \
    char* _base = lds + (BI) * 24576; \
    __builtin_amdgcn_global_load_lds((glb_u32*)_sa, (lds_u32*)(_base + w * 1024), 16, 0, 0); \
    __builtin_amdgcn_global_load_lds((glb_u32*)_sb, (lds_u32*)(_base + 8192 + w * 1024), 16, 0, 0); \
    __builtin_amdgcn_global_load_lds((glb_u32*)(_sb + (long)128 * ldb), (lds_u32*)(_base + 8192 + (8 + w) * 1024), 16, 0, 0); \
  } while (0)

  f32x4 acc[4][4];
#pragma unroll
  for (int i = 0; i < 4; ++i)
#pragma unroll
    for (int j = 0; j < 4; ++j)
      acc[i][j] = (f32x4){0.f, 0.f, 0.f, 0.f};

  STG32(0, 0);
  STG32(1, 1);
  asm volatile("s_waitcnt vmcnt(3)" ::: "memory");
  __builtin_amdgcn_s_barrier();

  int buf = 0;
  for (int g = 0; g < NT; ++g) {
    bool issue = (g + 2 < NT);
    if (issue) {
      int b2 = buf + 2; if (b2 >= 3) b2 -= 3;
      STG32(g + 2, b2);
    }

    const char* _Al = lds + buf * 24576;
    const char* _Bl = _Al + 8192;
    bf16x8 af[4], bf[4];
#pragma unroll
    for (int i = 0; i < 4; ++i)
      af[i] = *(const bf16x8*)(_Al + (wm * 4 + i) * 1024 + frag_off);
#pragma unroll
    for (int j = 0; j < 4; ++j)
      bf[j] = *(const bf16x8*)(_Bl + (wn * 4 + j) * 1024 + frag_off);

    asm volatile("s_waitcnt lgkmcnt(0)" ::: "memory");
    __builtin_amdgcn_sched_barrier(0);
    __builtin_amdgcn_s_setprio(1);
#pragma unroll
    for (int i = 0; i < 4; ++i)
#pragma unroll
      for (int j = 0; j < 4; ++j)
        acc[i][j] = __builtin_amdgcn_mfma_f32_16x16x32_bf16(af[i], bf[j], acc[i][j], 0, 0, 0);
    __builtin_amdgcn_s_setprio(0);

    if (issue) {
      asm volatile("s_waitcnt vmcnt(3)" ::: "memory");
    } else {
      asm volatile("s_waitcnt vmcnt(0)" ::: "memory");
    }
    __builtin_amdgcn_s_barrier();

    ++buf; if (buf >= 3) buf = 0;
  }
#undef STG32

  // epilogue: row = base + lhi*4 + reg, col = base + l15
#pragma unroll
  for (int i = 0; i < 4; ++i)
#pragma unroll
    for (int j = 0; j < 4; ++j) {
      int rl = wm * 64 + i * 16 + lhi * 4;
      int col = bn * 256 + wn * 64 + j * 16 + l15;
      f32x4 v = acc[i][j];
      if constexpr (CMODE == 5) {
        if (h == 0) {
          float* O = (float*)Cptr2 + (long)bz * S_LEN * 1024;
          int row = bm * 128 + rl;
#pragma unroll
          for (int r = 0; r < 4; ++r)
            O[(long)(row + r) * 1024 + col] = v[r];
        } else {
          // rows 1024..2047: part2[(batch*8 + bm-8)*128 + rl][col], f32
          float* Pp = (float*)Cptr + ((long)((bz * 8 + bm - 8) * 128 + rl)) * 1024 + col;
#pragma unroll
          for (int r = 0; r < 4; ++r)
            Pp[(long)r * 1024] = v[r];
        }
      } else {
        // fused QKV: cols [0,1024)=Q, [1024,2048)=K row-major bf16; [2048,3072)=V -> Vt[b][e][s]
        int r0 = bm * 128 + rl;
        if (col < 2048) {
          u16* dst = (u16*)Cptr + (col >= 1024 ? 8388608 : 0);
          int c = col & 1023;
#pragma unroll
          for (int r = 0; r < 4; ++r)
            dst[(long)(r0 + r) * 1024 + c] = f2bf(v[r]);
        } else {
          u16* Vt = (u16*)Cptr + 16777216;
          int e = col - 2048;
          int bb = r0 >> 11, s = r0 & 2047;
          ushort4 u;
          u.x = f2bf(v[0]); u.y = f2bf(v[1]); u.z = f2bf(v[2]); u.w = f2bf(v[3]);
          *reinterpret_cast<ushort4*>(Vt + ((long)bb * 1024 + e) * 2048 + s) = u;
        }
      }
    }
}

// ---------------- one-pass causal row softmax: sc(bf16, unscaled) -> P(bf16) ----------------
__global__ __launch_bounds__(256) void softmax1p(const u16* __restrict__ sc,
                                                 u16* __restrict__ P) {
  int q = blockIdx.x, b = blockIdx.y;
  const u16* srow = sc + ((long)b * S_LEN + q) * S_LEN;
  u16* prow = P + ((long)b * S_LEN + q) * S_LEN;
  int n = q + 1;
  int nz = ((q >> 7) + 1) << 7;   // zero-fill bound (128-band limit used by PV)
  int tid = threadIdx.x;
  int j0 = tid * 8;
  const float scale = 0.03125f;

  __shared__ float red[8];

  float vs[8];
#pragma unroll
  for (int e = 0; e < 8; ++e) vs[e] = -1e30f;
  if (j0 < n) {
    ushort4 a = *reinterpret_cast<const ushort4*>(srow + j0);
    ushort4 c = *reinterpret_cast<const ushort4*>(srow + j0 + 4);
    vs[0] = bf2f(a.x) * scale; vs[1] = bf2f(a.y) * scale;
    vs[2] = bf2f(a.z) * scale; vs[3] = bf2f(a.w) * scale;
    vs[4] = bf2f(c.x) * scale; vs[5] = bf2f(c.y) * scale;
    vs[6] = bf2f(c.z) * scale; vs[7] = bf2f(c.w) * scale;
#pragma unroll
    for (int e = 0; e < 8; ++e)
      if (j0 + e >= n) vs[e] = -1e30f;
  }

  float m = -1e30f;
#pragma unroll
  for (int e = 0; e < 8; ++e) m = fmaxf(m, vs[e]);
#pragma unroll
  for (int off = 32; off > 0; off >>= 1) m = fmaxf(m, __shfl_xor(m, off, 64));
  if ((tid & 63) == 0) red[tid >> 6] = m;
  __syncthreads();
  float ms = fmaxf(fmaxf(red[0], red[1]), fmaxf(red[2], red[3]));

  float p[8];
  float s = 0.f;
#pragma unroll
  for (int e = 0; e < 8; ++e) { p[e] = __expf(vs[e] - ms); s += (j0 + e < n) ? p[e] : 0.f; }
#pragma unroll
  for (int off = 32; off > 0; off >>= 1) s += __shfl_xor(s, off, 64);
  __syncthreads();
  if ((tid & 63) == 0) red[4 + (tid >> 6)] = s;
  __syncthreads();
  float inv = 1.f / (red[4] + red[5] + red[6] + red[7]);

  if (j0 < nz) {
    ushort4 o0, o1;
    o0.x = (j0 + 0 < n) ? f2bf(p[0] * inv) : (u16)0;
    o0.y = (j0 + 1 < n) ? f2bf(p[1] * inv) : (u16)0;
    o0.z = (j0 + 2 < n) ? f2bf(p[2] * inv) : (u16)0;
    o0.w = (j0 + 3 < n) ? f2bf(p[3] * inv) : (u16)0;
    o1.x = (j0 + 4 < n) ? f2bf(p[4] * inv) : (u16)0;
    o1.y = (j0 + 5 < n) ? f2bf(p[5] * inv) : (u16)0;
    o1.z = (j0 + 6 < n) ? f2bf(p[6] * inv) : (u16)0;
    o1.w = (j0 + 7 < n) ? f2bf(p[7] * inv) : (u16)0;
    *reinterpret_cast<ushort4*>(prow + j0) = o0;
    *reinterpret_cast<ushort4*>(prow + j0 + 4) = o1;
  }
}

// ---------------- add h=1 f32 partials into out rows [1024, 2048) ----------------
__global__ __launch_bounds__(256) void add_pv(const float4* __restrict__ p2,
                                              float4* __restrict__ out) {
  long i = (long)blockIdx.x * 256 + threadIdx.x;   // 4096*256 = 1,048,576 float4
  int c4 = (int)(i & 255);
  long rp = i >> 8;                                // [0, 4096): b*1024 + (row-1024)
  int b = (int)(rp >> 10), r = (int)(rp & 1023);
  long oo = ((long)(b * 2048 + 1024 + r) << 8) + c4;
  float4 a = out[oo], d = p2[i];
  a.x += d.x; a.y += d.y; a.z += d.z; a.w += d.w;
  out[oo] = a;
}

// ---------------- launch ----------------
extern "C" void kernel_launch(void* const* d_in, const int* in_sizes, int n_in,
                              void* d_out, int out_size, void* d_ws, size_t ws_size,
                              hipStream_t stream) {
  const float* x  = (const float*)d_in[0];
  const float* Wq = (const float*)d_in[1];
  const float* Wk = (const float*)d_in[2];
  const float* Wv = (const float*)d_in[3];
  float* out = (float*)d_out;

  // workspace layout (bytes):
  //  xb    [0,        16,777,216)
  //  wtb   [16.77M,   23,068,672)
  //  Qb    [23.07M,   39,845,888)
  //  Kb    [39.85M,   56,623,104)
  //  Vtb   [56.62M,   73,400,320)
  //  scb   [73.40M,  106,954,752)  bf16 scores (dead after softmax)
  //  part2 [73.40M,   90,177,536)  f32 PV h=1 partials [4][1024][1024] (reuses scb)
  //  P     [115.34M, 148,897,792)
  char* ws = (char*)d_ws;
  u16*   xb    = (u16*)(ws);
  u16*   wtb   = (u16*)(ws + 16777216);
  u16*   Qb    = (u16*)(ws + 23068672);
  u16*   Kb    = (u16*)(ws + 39845888);
  u16*   Vtb   = (u16*)(ws + 56623104);
  u16*   scb   = (u16*)(ws + 73400320);
  float* part2 = (float*)(ws + 73400320);
  u16*   P     = (u16*)(ws + 115343360);

  long nx = (long)NBATCH * S_LEN * DMODEL;
  convert_x_kernel<<<2048, 256, 0, stream>>>(x, xb, nx);

  transpose_w3_kernel<<<dim3(32, 32, 3), dim3(32, 8), 0, stream>>>(Wq, Wk, Wv, wtb);

  // fused QKV projection: M=8192, N=3072 (Q|K|V), K=1024; 768 blocks, XCD-swizzled
  gemm_bk32<3, 0><<<dim3(64, 12, 1), 512, 0, stream>>>(
      xb, wtb, Qb, nullptr, DMODEL, DMODEL, 0, DMODEL, 0, 0, 0);

  // scores (unscaled, bf16): per batch S = Q*K^T, causal skip; 256 blocks, XCD-swizzled
  gemm256_sc<<<dim3(8, 8, 4), 512, 0, stream>>>(
      Qb, Kb, scb, DMODEL, DMODEL, S_LEN, DMODEL,
      (long)S_LEN * DMODEL, (long)S_LEN * DMODEL, (long)S_LEN * S_LEN);

  softmax1p<<<dim3(S_LEN, NBATCH), 256, 0, stream>>>(scb, P);

  // O = P * V, 2 K-halves: h=0 -> f32 out direct; h=1 (bm>=8) -> f32 part2
  gemm_bk32<5, 4><<<dim3(16, 4, 8), 512, 0, stream>>>(
      P, Vtb, part2, out, S_LEN, S_LEN, 0, S_LEN,
      (long)S_LEN * S_LEN, (long)DMODEL * S_LEN, 0);

  // out rows [1024,2048) += part2
  add_pv<<<4096, 256, 0, stream>>>((const float4*)part2, (float4*)out);
}

// Round 12
// 170.672 us; speedup vs baseline: 1.0669x; 1.0176x over previous
//
#include <hip/hip_runtime.h>

#define S_LEN 2048
#define DMODEL 1024
#define NBATCH 4

typedef unsigned short u16;
typedef __bf16 bf16x8 __attribute__((ext_vector_type(8)));
typedef float f32x4 __attribute__((ext_vector_type(4)));

typedef __attribute__((address_space(3))) unsigned lds_u32;
typedef const __attribute__((address_space(1))) unsigned glb_u32;

__device__ __forceinline__ u16 f2bf(float f) {
  union { float f; unsigned u; } v;
  v.f = f;
  unsigned r = v.u + 0x7fffu + ((v.u >> 16) & 1u);
  return (u16)(r >> 16);
}

__device__ __forceinline__ float bf2f(u16 h) {
  union { unsigned u; float f; } v;
  v.u = ((unsigned)h) << 16;
  return v.f;
}

// ---------------- convert x: fp32 -> bf16, flat ----------------
__global__ void convert_x_kernel(const float* __restrict__ x, u16* __restrict__ xb, long n) {
  long i = ((long)blockIdx.x * blockDim.x + threadIdx.x) * 4;
  long stride = (long)gridDim.x * blockDim.x * 4;
  for (; i < n; i += stride) {
    float4 v = *reinterpret_cast<const float4*>(x + i);
    ushort4 o;
    o.x = f2bf(v.x); o.y = f2bf(v.y); o.z = f2bf(v.z); o.w = f2bf(v.w);
    *reinterpret_cast<ushort4*>(xb + i) = o;
  }
}

// ---------------- transpose-convert all 3 W: Wt[z][n][k] = bf16(W[k][n]) ----------------
__global__ void transpose_w3_kernel(const float* __restrict__ Wq, const float* __restrict__ Wk,
                                    const float* __restrict__ Wv, u16* __restrict__ Wt) {
  const float* W = blockIdx.z == 0 ? Wq : (blockIdx.z == 1 ? Wk : Wv);
  u16* dst = Wt + (long)blockIdx.z * 1024 * 1024;
  __shared__ float tile[32][33];
  int tx = threadIdx.x, ty = threadIdx.y;
  int k0 = blockIdx.x * 32, n0 = blockIdx.y * 32;
#pragma unroll
  for (int i = 0; i < 32; i += 8)
    tile[ty + i][tx] = W[(long)(k0 + ty + i) * DMODEL + n0 + tx];
  __syncthreads();
#pragma unroll
  for (int i = 0; i < 32; i += 8)
    dst[(long)(n0 + ty + i) * DMODEL + k0 + tx] = f2bf(tile[tx][ty + i]);
}

// ================= 256x256 NT GEMM, 4-phase/K-tile (r5 engine) =================
// MODE: 1 = scores (skip bn>bm, full K);
//       5 = PV half-split (bz = batch*2 + h; h=0: K=[0,min(1024,(bm+1)*256));
//           h=1: bm>=4 only, K=[1024,(bm+1)*256))
// CMODE: 1 = bf16 row-major (+bz*sCz); 6 = PV f32 (h=0 -> out direct, h=1 -> part2)
#define STG(SRCP, LD, ISB, H, T, BUFB) do { \
    const u16* _s = (SRCP) + (long)(H) * 128 * (LD) + (T) * 64; \
    char* _d = lds + (BUFB) * 65536 + ((ISB) ? 32768 : 0) + ((H) * 8 + w) * 2048; \
    __builtin_amdgcn_global_load_lds((glb_u32*)_s, (lds_u32*)_d, 16, 0, 0); \
    __builtin_amdgcn_global_load_lds((glb_u32*)(_s + 32), (lds_u32*)(_d + 1024), 16, 0, 0); \
  } while (0)

#define READ_A(QM) do { \
    _Pragma("unroll") \
    for (int _i = 0; _i < 4; ++_i) { \
      int _mp = (QM) * 8 + wm * 4 + _i; \
      af[_i][0] = *(const bf16x8*)(_Al + (_mp * 2 + 0) * 1024 + frag_off); \
      af[_i][1] = *(const bf16x8*)(_Al + (_mp * 2 + 1) * 1024 + frag_off); \
    } \
  } while (0)

#define READ_BQ(DST, QN) do { \
    _Pragma("unroll") \
    for (int _j = 0; _j < 2; ++_j) { \
      int _np = (QN) * 8 + wn * 2 + _j; \
      DST[_j][0] = *(const bf16x8*)(_Bl + (_np * 2 + 0) * 1024 + frag_off); \
      DST[_j][1] = *(const bf16x8*)(_Bl + (_np * 2 + 1) * 1024 + frag_off); \
    } \
  } while (0)

#define MFMA16(QM, QN, BREG) do { \
    _Pragma("unroll") \
    for (int _i = 0; _i < 4; ++_i) \
      _Pragma("unroll") \
      for (int _j = 0; _j < 2; ++_j) { \
        acc[QM][QN][_i][_j] = __builtin_amdgcn_mfma_f32_16x16x32_bf16(af[_i][0], BREG[_j][0], acc[QM][QN][_i][_j], 0, 0, 0); \
        acc[QM][QN][_i][_j] = __builtin_amdgcn_mfma_f32_16x16x32_bf16(af[_i][1], BREG[_j][1], acc[QM][QN][_i][_j], 0, 0, 0); \
      } \
  } while (0)

template<int CMODE, int MODE>
__global__ __launch_bounds__(512, 2) void gemm256(
    const u16* __restrict__ A, const u16* __restrict__ B,
    void* __restrict__ Cptr, void* __restrict__ Cptr2,
    int lda, int ldb, int ldc, int Kdim,
    long sAz, long sBz, long sCz)
{
  int bm = blockIdx.x, bn = blockIdx.y, bz = blockIdx.z;
  int k0 = 0, Keff = Kdim, h = 0;
  if constexpr (MODE == 1) {
    if (bn > bm) return;           // causal block skip
  }
  if constexpr (MODE == 5) {
    h = bz & 1;
    bz >>= 1;                      // batch
    int Klim = (bm + 1) * 256;
    if (h == 0) {
      Keff = Klim < 1024 ? Klim : 1024;
    } else {
      if (Klim <= 1024) return;
      k0 = 1024;
      Keff = Klim - 1024;
    }
  }
  int NT = Keff >> 6;   // K-tiles of 64; >= 4 in all launches

  const u16* Ab = A + (long)bz * sAz + (long)bm * 256 * lda + k0;
  const u16* Bb = B + (long)bz * sBz + (long)bn * 256 * ldb + k0;

  __shared__ char lds[131072];

  int tid = threadIdx.x;
  int lane = tid & 63, w = tid >> 6;
  int wm = w >> 2, wn = w & 3;
  int l15 = lane & 15, lhi = lane >> 4;
  int frag_off = (l15 * 64 + lhi * 16) ^ (((lane >> 3) & 1) << 5);

  int le = lane ^ ((lane >> 5) << 1);
  int lr = le >> 2;
  int kb = (le & 3) * 8;

  const u16* Asrc = Ab + (long)(w * 16 + lr) * lda + kb;
  const u16* Bsrc = Bb + (long)(w * 16 + lr) * ldb + kb;

  f32x4 acc[2][2][4][2];
#pragma unroll
  for (int a = 0; a < 2; ++a)
#pragma unroll
    for (int b = 0; b < 2; ++b)
#pragma unroll
      for (int c = 0; c < 4; ++c)
#pragma unroll
        for (int d = 0; d < 2; ++d)
          acc[a][b][c][d] = (f32x4){0.f, 0.f, 0.f, 0.f};

  STG(Asrc, lda, 0, 0, 0, 0); STG(Bsrc, ldb, 1, 0, 0, 0);
  STG(Asrc, lda, 0, 1, 0, 0); STG(Bsrc, ldb, 1, 1, 0, 0);
  STG(Asrc, lda, 0, 0, 1, 1); STG(Bsrc, ldb, 1, 0, 1, 1);
  asm volatile("s_waitcnt vmcnt(4)" ::: "memory");
  __builtin_amdgcn_s_barrier();

  for (int g = 0; g < NT; ++g) {
    int buf = g & 1;
    int t1 = g + 1; if (t1 >= NT) t1 -= NT;   // wrapped prefetch stays in-bounds;
    int t2 = g + 2; if (t2 >= NT) t2 -= NT;   // wrapped data never read
    const char* _Al = lds + buf * 65536;
    const char* _Bl = _Al + 32768;
    bf16x8 af[4][2], b0[2][2], b1[2][2];

    READ_A(0);
    READ_BQ(b0, 0);
    STG(Asrc, lda, 0, 1, t1, buf ^ 1);
    __builtin_amdgcn_s_barrier();
    asm volatile("s_waitcnt lgkmcnt(0)" ::: "memory");
    __builtin_amdgcn_sched_barrier(0);
    __builtin_amdgcn_s_setprio(1);
    MFMA16(0, 0, b0);
    __builtin_amdgcn_s_setprio(0);
    __builtin_amdgcn_s_barrier();

    READ_BQ(b1, 1);
    STG(Bsrc, ldb, 1, 1, t1, buf ^ 1);
    __builtin_amdgcn_s_barrier();
    asm volatile("s_waitcnt lgkmcnt(0)" ::: "memory");
    __builtin_amdgcn_sched_barrier(0);
    __builtin_amdgcn_s_setprio(1);
    MFMA16(0, 1, b1);
    __builtin_amdgcn_s_setprio(0);
    __builtin_amdgcn_s_barrier();

    READ_A(1);
    STG(Asrc, lda, 0, 0, t2, buf);
    __builtin_amdgcn_s_barrier();
    asm volatile("s_waitcnt lgkmcnt(0)" ::: "memory");
    __builtin_amdgcn_sched_barrier(0);
    __builtin_amdgcn_s_setprio(1);
    MFMA16(1, 1, b1);
    __builtin_amdgcn_s_setprio(0);
    __builtin_amdgcn_s_barrier();

    STG(Bsrc, ldb, 1, 0, t2, buf);
    __builtin_amdgcn_s_barrier();
    __builtin_amdgcn_s_setprio(1);
    MFMA16(1, 0, b0);
    __builtin_amdgcn_s_setprio(0);
    asm volatile("s_waitcnt vmcnt(4)" ::: "memory");
    __builtin_amdgcn_s_barrier();
  }

  int Mbase = bm * 256, Nbase = bn * 256;
#pragma unroll
  for (int qm = 0; qm < 2; ++qm)
#pragma unroll
    for (int qn = 0; qn < 2; ++qn)
#pragma unroll
      for (int i = 0; i < 4; ++i)
#pragma unroll
        for (int j = 0; j < 2; ++j) {
          int rl = qm * 128 + wm * 64 + i * 16 + lhi * 4;   // row within 256-band
          int col = Nbase + qn * 128 + wn * 32 + j * 16 + l15;
          f32x4 v = acc[qm][qn][i][j];
          if constexpr (CMODE == 1) {
            u16* C = (u16*)Cptr + (long)bz * sCz;
            int r0 = Mbase + rl;
#pragma unroll
            for (int r = 0; r < 4; ++r)
              C[(long)(r0 + r) * ldc + col] = f2bf(v[r]);
          } else {
            // PV f32 epilogue
            if (h == 0) {
              float* O = (float*)Cptr2 + (long)bz * S_LEN * 1024;
              int row = Mbase + rl;
#pragma unroll
              for (int r = 0; r < 4; ++r)
                O[(long)(row + r) * 1024 + col] = v[r];
            } else {
              // rows 1024..2047 -> part2[b*1024 + (row-1024)][col]
              float* Pp = (float*)Cptr + ((long)(bz * 1024 + (bm - 4) * 256 + rl)) * 1024 + col;
#pragma unroll
              for (int r = 0; r < 4; ++r)
                Pp[(long)r * 1024] = v[r];
            }
          }
        }
}

// ================= 128x256 NT GEMM, BK=32, 3-buffer depth-2 pipeline (proj) =================
__global__ __launch_bounds__(512) void gemm_proj(
    const u16* __restrict__ A, const u16* __restrict__ B, void* __restrict__ Cptr,
    int lda, int ldb, int Kdim)
{
  int bm = blockIdx.x, bn = blockIdx.y;
  int NT = Kdim >> 5;

  const u16* Ab = A + (long)bm * 128 * lda;
  const u16* Bb = B + (long)bn * 256 * ldb;

  __shared__ char lds[73728];   // 3 x 24 KiB

  int tid = threadIdx.x;
  int lane = tid & 63, w = tid >> 6;
  int wm = w >> 2, wn = w & 3;
  int l15 = lane & 15, lhi = lane >> 4;
  int frag_off = (l15 * 64 + lhi * 16) ^ (((lane >> 3) & 1) << 5);

  int le = lane ^ ((lane >> 5) << 1);
  int lr = le >> 2;
  int kb = (le & 3) * 8;

  const u16* Asrc = Ab + (long)(w * 16 + lr) * lda + kb;
  const u16* Bsrc = Bb + (long)(w * 16 + lr) * ldb + kb;

#define STG32(T, BI) do { \
    const u16* _sa = Asrc + (T) * 32; \
    const u16* _sb = Bsrc + (T) * 32; \
    char* _base = lds + (BI) * 24576; \
    __builtin_amdgcn_global_load_lds((glb_u32*)_sa, (lds_u32*)(_base + w * 1024), 16, 0, 0); \
    __builtin_amdgcn_global_load_lds((glb_u32*)_sb, (lds_u32*)(_base + 8192 + w * 1024), 16, 0, 0); \
    __builtin_amdgcn_global_load_lds((glb_u32*)(_sb + (long)128 * ldb), (lds_u32*)(_base + 8192 + (8 + w) * 1024), 16, 0, 0); \
  } while (0)

  f32x4 acc[4][4];
#pragma unroll
  for (int i = 0; i < 4; ++i)
#pragma unroll
    for (int j = 0; j < 4; ++j)
      acc[i][j] = (f32x4){0.f, 0.f, 0.f, 0.f};

  STG32(0, 0);
  STG32(1, 1);
  asm volatile("s_waitcnt vmcnt(3)" ::: "memory");
  __builtin_amdgcn_s_barrier();

  int buf = 0;
  for (int g = 0; g < NT; ++g) {
    bool issue = (g + 2 < NT);
    if (issue) {
      int b2 = buf + 2; if (b2 >= 3) b2 -= 3;
      STG32(g + 2, b2);
    }

    const char* _Al = lds + buf * 24576;
    const char* _Bl = _Al + 8192;
    bf16x8 af[4], bf[4];
#pragma unroll
    for (int i = 0; i < 4; ++i)
      af[i] = *(const bf16x8*)(_Al + (wm * 4 + i) * 1024 + frag_off);
#pragma unroll
    for (int j = 0; j < 4; ++j)
      bf[j] = *(const bf16x8*)(_Bl + (wn * 4 + j) * 1024 + frag_off);

    asm volatile("s_waitcnt lgkmcnt(0)" ::: "memory");
    __builtin_amdgcn_sched_barrier(0);
    __builtin_amdgcn_s_setprio(1);
#pragma unroll
    for (int i = 0; i < 4; ++i)
#pragma unroll
      for (int j = 0; j < 4; ++j)
        acc[i][j] = __builtin_amdgcn_mfma_f32_16x16x32_bf16(af[i], bf[j], acc[i][j], 0, 0, 0);
    __builtin_amdgcn_s_setprio(0);

    if (issue) {
      asm volatile("s_waitcnt vmcnt(3)" ::: "memory");
    } else {
      asm volatile("s_waitcnt vmcnt(0)" ::: "memory");
    }
    __builtin_amdgcn_s_barrier();

    ++buf; if (buf >= 3) buf = 0;
  }
#undef STG32

  // fused QKV epilogue: cols [0,1024)=Q, [1024,2048)=K row-major bf16; [2048,3072)=V -> Vt[b][e][s]
#pragma unroll
  for (int i = 0; i < 4; ++i)
#pragma unroll
    for (int j = 0; j < 4; ++j) {
      int rl = wm * 64 + i * 16 + lhi * 4;
      int col = bn * 256 + wn * 64 + j * 16 + l15;
      f32x4 v = acc[i][j];
      int r0 = bm * 128 + rl;
      if (col < 2048) {
        u16* dst = (u16*)Cptr + (col >= 1024 ? 8388608 : 0);
        int c = col & 1023;
#pragma unroll
        for (int r = 0; r < 4; ++r)
          dst[(long)(r0 + r) * 1024 + c] = f2bf(v[r]);
      } else {
        u16* Vt = (u16*)Cptr + 16777216;
        int e = col - 2048;
        int bb = r0 >> 11, s = r0 & 2047;
        ushort4 u;
        u.x = f2bf(v[0]); u.y = f2bf(v[1]); u.z = f2bf(v[2]); u.w = f2bf(v[3]);
        *reinterpret_cast<ushort4*>(Vt + ((long)bb * 1024 + e) * 2048 + s) = u;
      }
    }
}

// ---------------- one-pass causal row softmax: sc(bf16, unscaled) -> P(bf16) ----------------
__global__ __launch_bounds__(256) void softmax1p(const u16* __restrict__ sc,
                                                 u16* __restrict__ P) {
  int q = blockIdx.x, b = blockIdx.y;
  const u16* srow = sc + ((long)b * S_LEN + q) * S_LEN;
  u16* prow = P + ((long)b * S_LEN + q) * S_LEN;
  int n = q + 1;
  int nz = ((q >> 8) + 1) << 8;   // 256-aligned zero-fill bound (PV reads to (bm+1)*256)
  int tid = threadIdx.x;
  int j0 = tid * 8;
  const float scale = 0.03125f;

  __shared__ float red[8];

  float vs[8];
#pragma unroll
  for (int e = 0; e < 8; ++e) vs[e] = -1e30f;
  if (j0 < n) {
    ushort4 a = *reinterpret_cast<const ushort4*>(srow + j0);
    ushort4 c = *reinterpret_cast<const ushort4*>(srow + j0 + 4);
    vs[0] = bf2f(a.x) * scale; vs[1] = bf2f(a.y) * scale;
    vs[2] = bf2f(a.z) * scale; vs[3] = bf2f(a.w) * scale;
    vs[4] = bf2f(c.x) * scale; vs[5] = bf2f(c.y) * scale;
    vs[6] = bf2f(c.z) * scale; vs[7] = bf2f(c.w) * scale;
#pragma unroll
    for (int e = 0; e < 8; ++e)
      if (j0 + e >= n) vs[e] = -1e30f;
  }

  float m = -1e30f;
#pragma unroll
  for (int e = 0; e < 8; ++e) m = fmaxf(m, vs[e]);
#pragma unroll
  for (int off = 32; off > 0; off >>= 1) m = fmaxf(m, __shfl_xor(m, off, 64));
  if ((tid & 63) == 0) red[tid >> 6] = m;
  __syncthreads();
  float ms = fmaxf(fmaxf(red[0], red[1]), fmaxf(red[2], red[3]));

  float p[8];
  float s = 0.f;
#pragma unroll
  for (int e = 0; e < 8; ++e) { p[e] = __expf(vs[e] - ms); s += (j0 + e < n) ? p[e] : 0.f; }
#pragma unroll
  for (int off = 32; off > 0; off >>= 1) s += __shfl_xor(s, off, 64);
  __syncthreads();
  if ((tid & 63) == 0) red[4 + (tid >> 6)] = s;
  __syncthreads();
  float inv = 1.f / (red[4] + red[5] + red[6] + red[7]);

  if (j0 < nz) {
    ushort4 o0, o1;
    o0.x = (j0 + 0 < n) ? f2bf(p[0] * inv) : (u16)0;
    o0.y = (j0 + 1 < n) ? f2bf(p[1] * inv) : (u16)0;
    o0.z = (j0 + 2 < n) ? f2bf(p[2] * inv) : (u16)0;
    o0.w = (j0 + 3 < n) ? f2bf(p[3] * inv) : (u16)0;
    o1.x = (j0 + 4 < n) ? f2bf(p[4] * inv) : (u16)0;
    o1.y = (j0 + 5 < n) ? f2bf(p[5] * inv) : (u16)0;
    o1.z = (j0 + 6 < n) ? f2bf(p[6] * inv) : (u16)0;
    o1.w = (j0 + 7 < n) ? f2bf(p[7] * inv) : (u16)0;
    *reinterpret_cast<ushort4*>(prow + j0) = o0;
    *reinterpret_cast<ushort4*>(prow + j0 + 4) = o1;
  }
}

// ---------------- add h=1 f32 partials into out rows [1024, 2048) ----------------
__global__ __launch_bounds__(256) void add_pv(const float4* __restrict__ p2,
                                              float4* __restrict__ out) {
  long i = (long)blockIdx.x * 256 + threadIdx.x;   // 4096*256 = 1,048,576 float4
  int c4 = (int)(i & 255);
  long rp = i >> 8;                                // [0, 4096): b*1024 + (row-1024)
  int b = (int)(rp >> 10), r = (int)(rp & 1023);
  long oo = ((long)(b * 2048 + 1024 + r) << 8) + c4;
  float4 a = out[oo], d = p2[i];
  a.x += d.x; a.y += d.y; a.z += d.z; a.w += d.w;
  out[oo] = a;
}

// ---------------- launch ----------------
extern "C" void kernel_launch(void* const* d_in, const int* in_sizes, int n_in,
                              void* d_out, int out_size, void* d_ws, size_t ws_size,
                              hipStream_t stream) {
  const float* x  = (const float*)d_in[0];
  const float* Wq = (const float*)d_in[1];
  const float* Wk = (const float*)d_in[2];
  const float* Wv = (const float*)d_in[3];
  float* out = (float*)d_out;

  // workspace layout (bytes):
  //  xb    [0,        16,777,216)
  //  wtb   [16.77M,   23,068,672)
  //  Qb    [23.07M,   39,845,888)
  //  Kb    [39.85M,   56,623,104)
  //  Vtb   [56.62M,   73,400,320)
  //  scb   [73.40M,  106,954,752)  bf16 scores (dead after softmax)
  //  part2 [73.40M,   90,177,536)  f32 PV h=1 partials [4][1024][1024] (reuses scb)
  //  P     [115.34M, 148,897,792)
  char* ws = (char*)d_ws;
  u16*   xb    = (u16*)(ws);
  u16*   wtb   = (u16*)(ws + 16777216);
  u16*   Qb    = (u16*)(ws + 23068672);
  u16*   Kb    = (u16*)(ws + 39845888);
  u16*   Vtb   = (u16*)(ws + 56623104);
  u16*   scb   = (u16*)(ws + 73400320);
  float* part2 = (float*)(ws + 73400320);
  u16*   P     = (u16*)(ws + 115343360);

  long nx = (long)NBATCH * S_LEN * DMODEL;
  convert_x_kernel<<<2048, 256, 0, stream>>>(x, xb, nx);

  transpose_w3_kernel<<<dim3(32, 32, 3), dim3(32, 8), 0, stream>>>(Wq, Wk, Wv, wtb);

  // fused QKV projection: M=8192, N=3072 (Q|K|V), K=1024; plain blockIdx
  gemm_proj<<<dim3(64, 12, 1), 512, 0, stream>>>(xb, wtb, Qb, DMODEL, DMODEL, DMODEL);

  // scores (unscaled, bf16): per batch S = Q*K^T, causal skip
  gemm256<1, 1><<<dim3(8, 8, 4), 512, 0, stream>>>(
      Qb, Kb, scb, nullptr, DMODEL, DMODEL, S_LEN, DMODEL,
      (long)S_LEN * DMODEL, (long)S_LEN * DMODEL, (long)S_LEN * S_LEN);

  softmax1p<<<dim3(S_LEN, NBATCH), 256, 0, stream>>>(scb, P);

  // O = P * V on the 256^2 engine, 2 K-halves: h=0 -> f32 out; h=1 (bm>=4) -> f32 part2
  gemm256<6, 5><<<dim3(8, 4, 8), 512, 0, stream>>>(
      P, Vtb, part2, out, S_LEN, S_LEN, 0, S_LEN,
      (long)S_LEN * S_LEN, (long)DMODEL * S_LEN, 0);

  // out rows [1024,2048) += part2
  add_pv<<<4096, 256, 0, stream>>>((const float4*)part2, (float4*)out);
}

// Round 13
// 168.882 us; speedup vs baseline: 1.0782x; 1.0106x over previous
//
#include <hip/hip_runtime.h>

#define S_LEN 2048
#define DMODEL 1024
#define NBATCH 4

typedef unsigned short u16;
typedef __bf16 bf16x8 __attribute__((ext_vector_type(8)));
typedef float f32x4 __attribute__((ext_vector_type(4)));

typedef __attribute__((address_space(3))) unsigned lds_u32;
typedef const __attribute__((address_space(1))) unsigned glb_u32;

__device__ __forceinline__ u16 f2bf(float f) {
  union { float f; unsigned u; } v;
  v.f = f;
  unsigned r = v.u + 0x7fffu + ((v.u >> 16) & 1u);
  return (u16)(r >> 16);
}

__device__ __forceinline__ float bf2f(u16 h) {
  union { unsigned u; float f; } v;
  v.u = ((unsigned)h) << 16;
  return v.f;
}

// ---------------- convert x: fp32 -> bf16, flat ----------------
__global__ void convert_x_kernel(const float* __restrict__ x, u16* __restrict__ xb, long n) {
  long i = ((long)blockIdx.x * blockDim.x + threadIdx.x) * 4;
  long stride = (long)gridDim.x * blockDim.x * 4;
  for (; i < n; i += stride) {
    float4 v = *reinterpret_cast<const float4*>(x + i);
    ushort4 o;
    o.x = f2bf(v.x); o.y = f2bf(v.y); o.z = f2bf(v.z); o.w = f2bf(v.w);
    *reinterpret_cast<ushort4*>(xb + i) = o;
  }
}

// ---------------- transpose-convert all 3 W: Wt[z][n][k] = bf16(W[k][n]) ----------------
__global__ void transpose_w3_kernel(const float* __restrict__ Wq, const float* __restrict__ Wk,
                                    const float* __restrict__ Wv, u16* __restrict__ Wt) {
  const float* W = blockIdx.z == 0 ? Wq : (blockIdx.z == 1 ? Wk : Wv);
  u16* dst = Wt + (long)blockIdx.z * 1024 * 1024;
  __shared__ float tile[32][33];
  int tx = threadIdx.x, ty = threadIdx.y;
  int k0 = blockIdx.x * 32, n0 = blockIdx.y * 32;
#pragma unroll
  for (int i = 0; i < 32; i += 8)
    tile[ty + i][tx] = W[(long)(k0 + ty + i) * DMODEL + n0 + tx];
  __syncthreads();
#pragma unroll
  for (int i = 0; i < 32; i += 8)
    dst[(long)(n0 + ty + i) * DMODEL + k0 + tx] = f2bf(tile[tx][ty + i]);
}

// ================= 128x256 NT GEMM, BK=32, 3-buffer depth-2 pipeline =================
// (r10 engine, plain blockIdx.) MODE: 1 = scores (skip bn*2 > bm, full K);
//   4 = PV half-split (bz = batch*2 + h; K in [h*1024, min((h+1)*1024, (bm+1)*128)))
// CMODE: 1 = bf16 row-major (+bz*sCz); 5 = PV f32 (h=0 -> out direct; h=1 -> f32 part2)
template<int CMODE, int MODE>
__global__ __launch_bounds__(512) void gemm_bk32(
    const u16* __restrict__ A, const u16* __restrict__ B,
    void* __restrict__ Cptr, void* __restrict__ Cptr2,
    int lda, int ldb, int ldc, int Kdim,
    long sAz, long sBz, long sCz)
{
  int bm = blockIdx.x, bn = blockIdx.y, bz = blockIdx.z;
  int k0 = 0, Keff = Kdim, h = 0;
  if constexpr (MODE == 1) {
    if (bn * 2 > bm) return;   // block entirely above diagonal (128-row bands, 256-col)
  }
  if constexpr (MODE == 4) {
    h = bz & 1;
    bz >>= 1;                                  // batch
    int Klim = (bm + 1) * 128;
    k0 = h * 1024;
    if (k0 >= Klim) return;
    int k1 = k0 + 1024; if (k1 > Klim) k1 = Klim;
    Keff = k1 - k0;
  }
  int NT = Keff >> 5;   // K-steps of 32; >= 4 in all launches

  const u16* Ab = A + (long)bz * sAz + (long)bm * 128 * lda + k0;
  const u16* Bb = B + (long)bz * sBz + (long)bn * 256 * ldb + k0;

  __shared__ char lds[73728];   // 3 x 24 KiB

  int tid = threadIdx.x;
  int lane = tid & 63, w = tid >> 6;
  int wm = w >> 2, wn = w & 3;
  int l15 = lane & 15, lhi = lane >> 4;
  int frag_off = (l15 * 64 + lhi * 16) ^ (((lane >> 3) & 1) << 5);

  // staging source pre-swizzle (linear LDS dest, inverse-swizzled global src)
  int le = lane ^ ((lane >> 5) << 1);
  int lr = le >> 2;
  int kb = (le & 3) * 8;

  const u16* Asrc = Ab + (long)(w * 16 + lr) * lda + kb;
  const u16* Bsrc = Bb + (long)(w * 16 + lr) * ldb + kb;

#define STG32(T, BI) do { \
    const u16* _sa = Asrc + (T) * 32; \
    const u16* _sb = Bsrc + (T) * 32; \
    char* _base = lds + (BI) * 24576; \
    __builtin_amdgcn_global_load_lds((glb_u32*)_sa, (lds_u32*)(_base + w * 1024), 16, 0, 0); \
    __builtin_amdgcn_global_load_lds((glb_u32*)_sb, (lds_u32*)(_base + 8192 + w * 1024), 16, 0, 0); \
    __builtin_amdgcn_global_load_lds((glb_u32*)(_sb + (long)128 * ldb), (lds_u32*)(_base + 8192 + (8 + w) * 1024), 16, 0, 0); \
  } while (0)

  f32x4 acc[4][4];
#pragma unroll
  for (int i = 0; i < 4; ++i)
#pragma unroll
    for (int j = 0; j < 4; ++j)
      acc[i][j] = (f32x4){0.f, 0.f, 0.f, 0.f};

  // prologue: stages 0,1 in flight; vmcnt(3) -> stage 0 resident, stage 1 pending
  STG32(0, 0);
  STG32(1, 1);
  asm volatile("s_waitcnt vmcnt(3)" ::: "memory");
  __builtin_amdgcn_s_barrier();

  int buf = 0;
  for (int g = 0; g < NT; ++g) {
    bool issue = (g + 2 < NT);
    if (issue) {
      int b2 = buf + 2; if (b2 >= 3) b2 -= 3;
      STG32(g + 2, b2);
    }

    const char* _Al = lds + buf * 24576;
    const char* _Bl = _Al + 8192;
    bf16x8 af[4], bf[4];
#pragma unroll
    for (int i = 0; i < 4; ++i)
      af[i] = *(const bf16x8*)(_Al + (wm * 4 + i) * 1024 + frag_off);
#pragma unroll
    for (int j = 0; j < 4; ++j)
      bf[j] = *(const bf16x8*)(_Bl + (wn * 4 + j) * 1024 + frag_off);

    asm volatile("s_waitcnt lgkmcnt(0)" ::: "memory");
    __builtin_amdgcn_sched_barrier(0);
    __builtin_amdgcn_s_setprio(1);
#pragma unroll
    for (int i = 0; i < 4; ++i)
#pragma unroll
      for (int j = 0; j < 4; ++j)
        acc[i][j] = __builtin_amdgcn_mfma_f32_16x16x32_bf16(af[i], bf[j], acc[i][j], 0, 0, 0);
    __builtin_amdgcn_s_setprio(0);

    if (issue) {
      asm volatile("s_waitcnt vmcnt(3)" ::: "memory");   // stage g+1 resident; g+2 in flight
    } else {
      asm volatile("s_waitcnt vmcnt(0)" ::: "memory");   // tail drain
    }
    __builtin_amdgcn_s_barrier();

    ++buf; if (buf >= 3) buf = 0;
  }
#undef STG32

  // epilogue: row = base + lhi*4 + reg, col = base + l15
#pragma unroll
  for (int i = 0; i < 4; ++i)
#pragma unroll
    for (int j = 0; j < 4; ++j) {
      int rl = wm * 64 + i * 16 + lhi * 4;            // row within 128-band
      int col = bn * 256 + wn * 64 + j * 16 + l15;    // global col
      f32x4 v = acc[i][j];
      if constexpr (CMODE == 1) {
        u16* C = (u16*)Cptr + (long)bz * sCz;
        int r0 = bm * 128 + rl;
#pragma unroll
        for (int r = 0; r < 4; ++r)
          C[(long)(r0 + r) * ldc + col] = f2bf(v[r]);
      } else {
        // CMODE 5: PV f32 epilogue
        if (h == 0) {
          float* O = (float*)Cptr2 + (long)bz * S_LEN * 1024;
          int row = bm * 128 + rl;
#pragma unroll
          for (int r = 0; r < 4; ++r)
            O[(long)(row + r) * 1024 + col] = v[r];
        } else {
          // rows 1024..2047 -> part2[(batch*8 + bm-8)*128 + rl][col], f32
          float* Pp = (float*)Cptr + ((long)((bz * 8 + bm - 8) * 128 + rl)) * 1024 + col;
#pragma unroll
          for (int r = 0; r < 4; ++r)
            Pp[(long)r * 1024] = v[r];
        }
      }
    }
}

// ================= 128x256 NT GEMM proj (r12, measured 62.0 us) =================
__global__ __launch_bounds__(512) void gemm_proj(
    const u16* __restrict__ A, const u16* __restrict__ B, void* __restrict__ Cptr,
    int lda, int ldb, int Kdim)
{
  int bm = blockIdx.x, bn = blockIdx.y;
  int NT = Kdim >> 5;

  const u16* Ab = A + (long)bm * 128 * lda;
  const u16* Bb = B + (long)bn * 256 * ldb;

  __shared__ char lds[73728];

  int tid = threadIdx.x;
  int lane = tid & 63, w = tid >> 6;
  int wm = w >> 2, wn = w & 3;
  int l15 = lane & 15, lhi = lane >> 4;
  int frag_off = (l15 * 64 + lhi * 16) ^ (((lane >> 3) & 1) << 5);

  int le = lane ^ ((lane >> 5) << 1);
  int lr = le >> 2;
  int kb = (le & 3) * 8;

  const u16* Asrc = Ab + (long)(w * 16 + lr) * lda + kb;
  const u16* Bsrc = Bb + (long)(w * 16 + lr) * ldb + kb;

#define STG32(T, BI) do { \
    const u16* _sa = Asrc + (T) * 32; \
    const u16* _sb = Bsrc + (T) * 32; \
    char* _base = lds + (BI) * 24576; \
    __builtin_amdgcn_global_load_lds((glb_u32*)_sa, (lds_u32*)(_base + w * 1024), 16, 0, 0); \
    __builtin_amdgcn_global_load_lds((glb_u32*)_sb, (lds_u32*)(_base + 8192 + w * 1024), 16, 0, 0); \
    __builtin_amdgcn_global_load_lds((glb_u32*)(_sb + (long)128 * ldb), (lds_u32*)(_base + 8192 + (8 + w) * 1024), 16, 0, 0); \
  } while (0)

  f32x4 acc[4][4];
#pragma unroll
  for (int i = 0; i < 4; ++i)
#pragma unroll
    for (int j = 0; j < 4; ++j)
      acc[i][j] = (f32x4){0.f, 0.f, 0.f, 0.f};

  STG32(0, 0);
  STG32(1, 1);
  asm volatile("s_waitcnt vmcnt(3)" ::: "memory");
  __builtin_amdgcn_s_barrier();

  int buf = 0;
  for (int g = 0; g < NT; ++g) {
    bool issue = (g + 2 < NT);
    if (issue) {
      int b2 = buf + 2; if (b2 >= 3) b2 -= 3;
      STG32(g + 2, b2);
    }

    const char* _Al = lds + buf * 24576;
    const char* _Bl = _Al + 8192;
    bf16x8 af[4], bf[4];
#pragma unroll
    for (int i = 0; i < 4; ++i)
      af[i] = *(const bf16x8*)(_Al + (wm * 4 + i) * 1024 + frag_off);
#pragma unroll
    for (int j = 0; j < 4; ++j)
      bf[j] = *(const bf16x8*)(_Bl + (wn * 4 + j) * 1024 + frag_off);

    asm volatile("s_waitcnt lgkmcnt(0)" ::: "memory");
    __builtin_amdgcn_sched_barrier(0);
    __builtin_amdgcn_s_setprio(1);
#pragma unroll
    for (int i = 0; i < 4; ++i)
#pragma unroll
      for (int j = 0; j < 4; ++j)
        acc[i][j] = __builtin_amdgcn_mfma_f32_16x16x32_bf16(af[i], bf[j], acc[i][j], 0, 0, 0);
    __builtin_amdgcn_s_setprio(0);

    if (issue) {
      asm volatile("s_waitcnt vmcnt(3)" ::: "memory");
    } else {
      asm volatile("s_waitcnt vmcnt(0)" ::: "memory");
    }
    __builtin_amdgcn_s_barrier();

    ++buf; if (buf >= 3) buf = 0;
  }
#undef STG32

  // fused QKV epilogue: cols [0,1024)=Q, [1024,2048)=K row-major bf16; [2048,3072)=V -> Vt[b][e][s]
#pragma unroll
  for (int i = 0; i < 4; ++i)
#pragma unroll
    for (int j = 0; j < 4; ++j) {
      int rl = wm * 64 + i * 16 + lhi * 4;
      int col = bn * 256 + wn * 64 + j * 16 + l15;
      f32x4 v = acc[i][j];
      int r0 = bm * 128 + rl;
      if (col < 2048) {
        u16* dst = (u16*)Cptr + (col >= 1024 ? 8388608 : 0);
        int c = col & 1023;
#pragma unroll
        for (int r = 0; r < 4; ++r)
          dst[(long)(r0 + r) * 1024 + c] = f2bf(v[r]);
      } else {
        u16* Vt = (u16*)Cptr + 16777216;
        int e = col - 2048;
        int bb = r0 >> 11, s = r0 & 2047;
        ushort4 u;
        u.x = f2bf(v[0]); u.y = f2bf(v[1]); u.z = f2bf(v[2]); u.w = f2bf(v[3]);
        *reinterpret_cast<ushort4*>(Vt + ((long)bb * 1024 + e) * 2048 + s) = u;
      }
    }
}

// ---------------- one-pass causal row softmax: sc(bf16, unscaled) -> P(bf16) ----------------
__global__ __launch_bounds__(256) void softmax1p(const u16* __restrict__ sc,
                                                 u16* __restrict__ P) {
  int q = blockIdx.x, b = blockIdx.y;
  const u16* srow = sc + ((long)b * S_LEN + q) * S_LEN;
  u16* prow = P + ((long)b * S_LEN + q) * S_LEN;
  int n = q + 1;
  int nz = ((q >> 7) + 1) << 7;   // 128-aligned zero-fill (PV reads to (bm+1)*128)
  int tid = threadIdx.x;
  int j0 = tid * 8;
  const float scale = 0.03125f;

  __shared__ float red[8];

  float vs[8];
#pragma unroll
  for (int e = 0; e < 8; ++e) vs[e] = -1e30f;
  if (j0 < n) {
    ushort4 a = *reinterpret_cast<const ushort4*>(srow + j0);
    ushort4 c = *reinterpret_cast<const ushort4*>(srow + j0 + 4);
    vs[0] = bf2f(a.x) * scale; vs[1] = bf2f(a.y) * scale;
    vs[2] = bf2f(a.z) * scale; vs[3] = bf2f(a.w) * scale;
    vs[4] = bf2f(c.x) * scale; vs[5] = bf2f(c.y) * scale;
    vs[6] = bf2f(c.z) * scale; vs[7] = bf2f(c.w) * scale;
#pragma unroll
    for (int e = 0; e < 8; ++e)
      if (j0 + e >= n) vs[e] = -1e30f;
  }

  float m = -1e30f;
#pragma unroll
  for (int e = 0; e < 8; ++e) m = fmaxf(m, vs[e]);
#pragma unroll
  for (int off = 32; off > 0; off >>= 1) m = fmaxf(m, __shfl_xor(m, off, 64));
  if ((tid & 63) == 0) red[tid >> 6] = m;
  __syncthreads();
  float ms = fmaxf(fmaxf(red[0], red[1]), fmaxf(red[2], red[3]));

  float p[8];
  float s = 0.f;
#pragma unroll
  for (int e = 0; e < 8; ++e) { p[e] = __expf(vs[e] - ms); s += (j0 + e < n) ? p[e] : 0.f; }
#pragma unroll
  for (int off = 32; off > 0; off >>= 1) s += __shfl_xor(s, off, 64);
  __syncthreads();
  if ((tid & 63) == 0) red[4 + (tid >> 6)] = s;
  __syncthreads();
  float inv = 1.f / (red[4] + red[5] + red[6] + red[7]);

  if (j0 < nz) {
    ushort4 o0, o1;
    o0.x = (j0 + 0 < n) ? f2bf(p[0] * inv) : (u16)0;
    o0.y = (j0 + 1 < n) ? f2bf(p[1] * inv) : (u16)0;
    o0.z = (j0 + 2 < n) ? f2bf(p[2] * inv) : (u16)0;
    o0.w = (j0 + 3 < n) ? f2bf(p[3] * inv) : (u16)0;
    o1.x = (j0 + 4 < n) ? f2bf(p[4] * inv) : (u16)0;
    o1.y = (j0 + 5 < n) ? f2bf(p[5] * inv) : (u16)0;
    o1.z = (j0 + 6 < n) ? f2bf(p[6] * inv) : (u16)0;
    o1.w = (j0 + 7 < n) ? f2bf(p[7] * inv) : (u16)0;
    *reinterpret_cast<ushort4*>(prow + j0) = o0;
    *reinterpret_cast<ushort4*>(prow + j0 + 4) = o1;
  }
}

// ---------------- add h=1 f32 partials into out rows [1024, 2048) ----------------
__global__ __launch_bounds__(256) void add_pv(const float4* __restrict__ p2,
                                              float4* __restrict__ out) {
  long i = (long)blockIdx.x * 256 + threadIdx.x;   // 4096*256 = 1,048,576 float4
  int c4 = (int)(i & 255);
  long rp = i >> 8;                                // [0, 4096): b*1024 + (row-1024)
  int b = (int)(rp >> 10), r = (int)(rp & 1023);
  long oo = ((long)(b * 2048 + 1024 + r) << 8) + c4;
  float4 a = out[oo], d = p2[i];
  a.x += d.x; a.y += d.y; a.z += d.z; a.w += d.w;
  out[oo] = a;
}

// ---------------- launch ----------------
extern "C" void kernel_launch(void* const* d_in, const int* in_sizes, int n_in,
                              void* d_out, int out_size, void* d_ws, size_t ws_size,
                              hipStream_t stream) {
  const float* x  = (const float*)d_in[0];
  const float* Wq = (const float*)d_in[1];
  const float* Wk = (const float*)d_in[2];
  const float* Wv = (const float*)d_in[3];
  float* out = (float*)d_out;

  // workspace layout (bytes):
  //  xb    [0,        16,777,216)
  //  wtb   [16.77M,   23,068,672)
  //  Qb    [23.07M,   39,845,888)
  //  Kb    [39.85M,   56,623,104)
  //  Vtb   [56.62M,   73,400,320)
  //  scb   [73.40M,  106,954,752)  bf16 scores (dead after softmax)
  //  part2 [73.40M,   90,177,536)  f32 PV h=1 partials [4][1024][1024] (reuses scb)
  //  P     [115.34M, 148,897,792)
  char* ws = (char*)d_ws;
  u16*   xb    = (u16*)(ws);
  u16*   wtb   = (u16*)(ws + 16777216);
  u16*   Qb    = (u16*)(ws + 23068672);
  u16*   Kb    = (u16*)(ws + 39845888);
  u16*   Vtb   = (u16*)(ws + 56623104);
  u16*   scb   = (u16*)(ws + 73400320);
  float* part2 = (float*)(ws + 73400320);
  u16*   P     = (u16*)(ws + 115343360);

  long nx = (long)NBATCH * S_LEN * DMODEL;
  convert_x_kernel<<<2048, 256, 0, stream>>>(x, xb, nx);

  transpose_w3_kernel<<<dim3(32, 32, 3), dim3(32, 8), 0, stream>>>(Wq, Wk, Wv, wtb);

  // fused QKV projection: M=8192, N=3072 (Q|K|V), K=1024
  gemm_proj<<<dim3(64, 12, 1), 512, 0, stream>>>(xb, wtb, Qb, DMODEL, DMODEL, DMODEL);

  // scores (unscaled, bf16): 128-row bands, 256-col blocks, skip bn*2>bm -> 288 active
  gemm_bk32<1, 1><<<dim3(16, 8, 4), 512, 0, stream>>>(
      Qb, Kb, scb, nullptr, DMODEL, DMODEL, S_LEN, DMODEL,
      (long)S_LEN * DMODEL, (long)S_LEN * DMODEL, (long)S_LEN * S_LEN);

  softmax1p<<<dim3(S_LEN, NBATCH), 256, 0, stream>>>(scb, P);

  // O = P * V, 128-bands, 2 K-halves: h=0 -> f32 out direct; h=1 (bm>=8) -> f32 part2
  gemm_bk32<5, 4><<<dim3(16, 4, 8), 512, 0, stream>>>(
      P, Vtb, part2, out, S_LEN, S_LEN, 0, S_LEN,
      (long)S_LEN * S_LEN, (long)DMODEL * S_LEN, 0);

  // out rows [1024,2048) += part2
  add_pv<<<4096, 256, 0, stream>>>((const float4*)part2, (float4*)out);
}